// Round 14
// baseline (1480.575 us; speedup 1.0000x reference)
//
#include <hip/hip_runtime.h>
#include <math.h>

#define NN   24          // nodes per graph
#define EPB  32          // graph elements per block (8 threads/elem: halves LDS reads/elem)
#define CSTR 28          // LDS column stride (floats): 24 + 4 pad, 16B aligned
#define ESTR 452         // per-elem stride: 16*28 + 4 → e-stride ≡ 4 banks mod 32
#define T    256

typedef float v2f __attribute__((ext_vector_type(2)));

// ws layout (floats): [0..575] A(24x24) | [576..2111] Wc(768x2) | [2112..2113] bc(2)

__global__ void prep_kernel(const int* __restrict__ ei, int ec,
                            const float* __restrict__ fcw1, const float* __restrict__ fcb1,
                            const float* __restrict__ fcw2, const float* __restrict__ fcb2,
                            float* __restrict__ ws) {
  int t = threadIdx.x;
  if (blockIdx.x == 0) {
    __shared__ float deg[NN];
    __shared__ float dinv[NN];
    __shared__ float As[NN*NN];
    __shared__ int s_is64;
    if (t == 0) s_is64 = 1;
    if (t < NN) deg[t] = 1.0f;            // self-loop contribution
    for (int k = t; k < NN*NN; k += T) As[k] = 0.0f;
    __syncthreads();
    // dtype sniff: int64 edge_index viewed as int32 has all odd (high) words == 0
    for (int k = t; k < 2*ec; k += T) {
      if (ei[2*k + 1] != 0) atomicExch(&s_is64, 0);
    }
    __syncthreads();
    int is64 = s_is64;
    for (int k = t; k < ec; k += T) {
      int d = is64 ? ei[2*(ec + k)] : ei[ec + k];
      atomicAdd(&deg[d], 1.0f);
    }
    __syncthreads();
    if (t < NN) dinv[t] = 1.0f / sqrtf(deg[t]);
    __syncthreads();
    for (int k = t; k < ec; k += T) {
      int s = is64 ? ei[2*k]        : ei[k];
      int d = is64 ? ei[2*(ec + k)] : ei[ec + k];
      atomicAdd(&As[d*NN + s], dinv[s]*dinv[d]);
    }
    if (t < NN) atomicAdd(&As[t*NN + t], dinv[t]*dinv[t]);  // self loop
    __syncthreads();
    for (int k = t; k < NN*NN; k += T) ws[k] = As[k];
    if (t < 2) {
      float acc = fcb2[t];
      for (int k = 0; k < 128; ++k) acc += fcb1[k]*fcw2[k*2 + t];
      ws[2112 + t] = acc;
    }
  } else {
    // Wc = fcw1 @ fcw2 : blocks 1..8 compute 96 rows each
    int r0 = (blockIdx.x - 1) * 96;
    for (int idx = t; idx < 96*2; idx += T) {
      int r = r0 + (idx >> 1), c = idx & 1;
      float acc = 0.f;
      for (int k = 0; k < 128; ++k) acc += fcw1[r*128 + k]*fcw2[k*2 + c];
      ws[576 + r*2 + c] = acc;
    }
  }
}

// Feature-paired merged step (EPB=32): thread owns COLUMN-PAIR (f, f+1) of one
// elem; hh[i] = (h[i][f], h[i][f+1]) — one read of each g-column serves two
// outputs. NT = EPB*FOUT/2 ∈ {64,128,256} so chunk = t/NT is wave-uniform by
// construction. W-mix (pk-fma) → relu → BARRIER → A-mix per row-pair → float2
// writes into both columns in place. Live set: hh[24] v2f = 48 floats
// (R12-proven spill-free at (256,2)).
template<int FIN, int FOUT, int SPLIT>
__device__ __forceinline__ void merged_fp(const float* __restrict__ Ag, float* gbuf,
                                          const float* Ws, const float* bs, int t) {
  constexpr int FP = FOUT/2;            // 2,2,4,4,8,8
  constexpr int NT = EPB*FP;            // 64,64,128,128,256,256
  constexpr int CL = NN/SPLIT;          // 6,6,12,12,24,24
  int task  = t & (NT - 1);
  int i0    = (t / NT) * CL;            // wave-uniform (NT >= 64)
  int e = task / FP;
  int f = (task % FP) * 2;
  const float* ib = gbuf + e*ESTR;
  float2 bb = *(const float2*)(bs + f);
  v2f hh[NN];
  #pragma unroll
  for (int i = 0; i < NN; ++i) hh[i] = (v2f){bb.x, bb.y};
  #pragma unroll
  for (int fi = 0; fi < FIN; ++fi) {
    float2 wp = *(const float2*)(Ws + fi*FOUT + f);
    v2f w2 = (v2f){wp.x, wp.y};
    const float4* c4 = (const float4*)(ib + fi*CSTR);
    #pragma unroll
    for (int k = 0; k < 6; ++k) {
      float4 v = c4[k];
      hh[4*k+0] = (v2f){v.x, v.x}*w2 + hh[4*k+0];   // v_pk_fma_f32
      hh[4*k+1] = (v2f){v.y, v.y}*w2 + hh[4*k+1];
      hh[4*k+2] = (v2f){v.z, v.z}*w2 + hh[4*k+2];
      hh[4*k+3] = (v2f){v.w, v.w}*w2 + hh[4*k+3];
    }
  }
  {
    v2f z2 = (v2f){0.f, 0.f};
    #pragma unroll
    for (int i = 0; i < NN; ++i) hh[i] = __builtin_elementwise_max(hh[i], z2);
  }
  __syncthreads();           // all gbuf reads complete before in-place overwrite
  float* colA = gbuf + e*ESTR + f*CSTR;
  float* colB = colA + CSTR;
  #pragma unroll
  for (int ii = 0; ii < CL; ii += 2) {
    int iA = i0 + ii;
    const float* ArA = Ag + iA*NN;        // wave-uniform rows → s_load
    const float* ArB = ArA + NN;
    v2f a0 = (v2f){0.f, 0.f}, a1 = (v2f){0.f, 0.f};
    #pragma unroll
    for (int j = 0; j < NN; ++j) {
      a0 = (v2f){ArA[j], ArA[j]}*hh[j] + a0;
      a1 = (v2f){ArB[j], ArB[j]}*hh[j] + a1;
    }
    *(float2*)(colA + iA) = make_float2(a0.x, a1.x);
    *(float2*)(colB + iA) = make_float2(a0.y, a1.y);
  }
}

// (256,2): relaxed bound — allocator grants the 48-float hh live set without
// spilling (R12: 72 VGPR, lowest-ever scratch). Tight bounds clamp & spill.
// T=256 4-wave blocks are the only allocator regime observed to behave.
__global__ __launch_bounds__(T, 2) void gcn_main(
    const float* __restrict__ x, const float* __restrict__ ws,
    const float* __restrict__ W1, const float* __restrict__ b1,
    const float* __restrict__ W2, const float* __restrict__ b2,
    const float* __restrict__ W3, const float* __restrict__ b3,
    const float* __restrict__ W4, const float* __restrict__ b4,
    const float* __restrict__ W5, const float* __restrict__ b5,
    const float* __restrict__ W6, const float* __restrict__ b6,
    const float* __restrict__ W7, const float* __restrict__ b7,
    float* __restrict__ out) {
  __shared__ __align__(16) float gbuf[EPB*ESTR];  // 57856 B, single in-place buffer
  __shared__ __align__(16) float Wsh[500];        // W1..W6; W7 read from global/L1
  __shared__ __align__(16) float bsh[88];
  int t = threadIdx.x;

  // stage layer weights/biases into LDS
  {
    const float* Wp[6] = {W1,W2,W3,W4,W5,W6};
    const float* bp[7] = {b1,b2,b3,b4,b5,b6,b7};
    const int wsz[6] = {4,16,32,64,128,256};
    const int wof[6] = {0,4,20,52,116,244};
    const int bsz[7] = {4,4,8,8,16,16,32};
    const int bof[7] = {0,4,8,16,24,40,56};
    #pragma unroll
    for (int l = 0; l < 6; ++l) {
      for (int k = t; k < wsz[l]; k += T) Wsh[wof[l] + k] = Wp[l][k];
    }
    #pragma unroll
    for (int l = 0; l < 7; ++l) {
      if (t < bsz[l]) bsh[bof[l] + t] = bp[l][t];
    }
  }
  // stage x tile into column slot 1 of each elem (col 0 gets g1 = A@x)
  {
    const float* xg = x + (size_t)blockIdx.x * (EPB*NN);
    if (t < EPB*NN/4) {              // 192 float4
      float4 v = ((const float4*)xg)[t];
      int e = t/6, k = t - e*6;
      ((float4*)(gbuf + e*ESTR + CSTR))[k] = v;
    }
  }
  __syncthreads();

  // g1 = A @ x : 768 tasks (e, i) over 3 iterations; A rows per-lane (L1-hot)
  #pragma unroll
  for (int it = 0; it < 3; ++it) {
    int idx = t + it*T;
    int e = idx & 31, i = idx >> 5;      // i in 0..23
    const float4* xv = (const float4*)(gbuf + e*ESTR + CSTR);
    const float4* Ar = (const float4*)(ws + i*NN);
    float acc = 0.f;
    #pragma unroll
    for (int k = 0; k < 6; ++k) {
      float4 a = Ar[k]; float4 v = xv[k];
      acc += a.x*v.x + a.y*v.y + a.z*v.z + a.w*v.w;
    }
    gbuf[e*ESTR + i] = acc;
  }
  __syncthreads();

  merged_fp<1, 4, 4>(ws, gbuf, Wsh+0,   bsh+0,  t); __syncthreads();
  merged_fp<4, 4, 4>(ws, gbuf, Wsh+4,   bsh+4,  t); __syncthreads();
  merged_fp<4, 8, 2>(ws, gbuf, Wsh+20,  bsh+8,  t); __syncthreads();
  merged_fp<8, 8, 2>(ws, gbuf, Wsh+52,  bsh+16, t); __syncthreads();
  merged_fp<8,16, 1>(ws, gbuf, Wsh+116, bsh+24, t); __syncthreads();
  merged_fp<16,16,1>(ws, gbuf, Wsh+244, bsh+40, t); __syncthreads();

  // L7 + composed FC + log_softmax: 8 threads/elem, each does 2 sequential
  // feature-pair passes (fp = q, q+8). hh[24] v2f per pass (48 floats, proven
  // spill-free). p = (p0,p1) accumulates across both passes; 8-lane butterfly.
  {
    const float* Wc = ws + 576;
    float bc0 = ws[2112], bc1 = ws[2113];
    v2f z2 = (v2f){0.f, 0.f};
    int e = t >> 3;                  // elem 0..31
    int q = t & 7;                   // sub-task
    const float* ib = gbuf + e*ESTR;
    v2f p = (v2f){0.f, 0.f};         // (p0, p1)
    #pragma unroll
    for (int r = 0; r < 2; ++r) {
      int f = (q + r*8) * 2;         // feature pairs 0..15
      v2f bb = (v2f){bsh[56 + f], bsh[56 + f + 1]};
      v2f hh[NN];
      #pragma unroll
      for (int i = 0; i < NN; ++i) hh[i] = bb;
      #pragma unroll
      for (int fi = 0; fi < 16; ++fi) {
        float2 wp = *(const float2*)(W7 + fi*32 + f);   // global, L1-hot
        v2f w2 = (v2f){wp.x, wp.y};
        const float4* c4 = (const float4*)(ib + fi*CSTR);
        #pragma unroll
        for (int k = 0; k < 6; ++k) {
          float4 v = c4[k];
          hh[4*k+0] = (v2f){v.x, v.x}*w2 + hh[4*k+0];
          hh[4*k+1] = (v2f){v.y, v.y}*w2 + hh[4*k+1];
          hh[4*k+2] = (v2f){v.z, v.z}*w2 + hh[4*k+2];
          hh[4*k+3] = (v2f){v.w, v.w}*w2 + hh[4*k+3];
        }
      }
      #pragma unroll
      for (int i = 0; i < NN; ++i) {
        v2f h = __builtin_elementwise_max(hh[i], z2);
        float4 c = *(const float4*)(Wc + (i*32 + f)*2); // (wc0_f,wc1_f,wc0_f1,wc1_f1)
        p = (v2f){h.x, h.x}*(v2f){c.x, c.y} + p;
        p = (v2f){h.y, h.y}*(v2f){c.z, c.w} + p;
      }
    }
    float p0 = p.x, p1 = p.y;
    #pragma unroll
    for (int m = 1; m < 8; m <<= 1) {
      p0 += __shfl_xor(p0, m, 8);
      p1 += __shfl_xor(p1, m, 8);
    }
    if (q == 0) {
      float z0 = p0 + bc0, z1 = p1 + bc1;
      float mx = fmaxf(z0, z1);
      float lse = mx + logf(expf(z0 - mx) + expf(z1 - mx));
      int eg = blockIdx.x*EPB + e;
      *(float2*)(out + eg*2) = make_float2(z0 - lse, z1 - lse);
    }
  }
}

extern "C" void kernel_launch(void* const* d_in, const int* in_sizes, int n_in,
                              void* d_out, int out_size, void* d_ws, size_t ws_size,
                              hipStream_t stream) {
  const float* x    = (const float*)d_in[0];
  const int*   ei   = (const int*)  d_in[1];
  const float* W1   = (const float*)d_in[2];  const float* b1 = (const float*)d_in[3];
  const float* W2   = (const float*)d_in[4];  const float* b2 = (const float*)d_in[5];
  const float* W3   = (const float*)d_in[6];  const float* b3 = (const float*)d_in[7];
  const float* W4   = (const float*)d_in[8];  const float* b4 = (const float*)d_in[9];
  const float* W5   = (const float*)d_in[10]; const float* b5 = (const float*)d_in[11];
  const float* W6   = (const float*)d_in[12]; const float* b6 = (const float*)d_in[13];
  const float* W7   = (const float*)d_in[14]; const float* b7 = (const float*)d_in[15];
  const float* fcw1 = (const float*)d_in[16]; const float* fcb1 = (const float*)d_in[17];
  const float* fcw2 = (const float*)d_in[18]; const float* fcb2 = (const float*)d_in[19];
  float* out = (float*)d_out;
  float* ws  = (float*)d_ws;
  int ec = in_sizes[1] / 2;        // 96 edges
  int B  = in_sizes[0] / NN;       // 32768

  hipLaunchKernelGGL(prep_kernel, dim3(9), dim3(T), 0, stream,
                     ei, ec, fcw1, fcb1, fcw2, fcb2, ws);
  hipLaunchKernelGGL(gcn_main, dim3(B/EPB), dim3(T), 0, stream,
                     x, ws, W1,b1, W2,b2, W3,b3, W4,b4, W5,b5, W6,b6, W7,b7, out);
}

// Round 15
// 207.580 us; speedup vs baseline: 7.1326x; 7.1326x over previous
//
#include <hip/hip_runtime.h>
#include <math.h>

#define NN   24          // nodes per graph
#define EPB  16          // graph elements per block
#define CSTR 28          // LDS column stride (floats): 24 + 4 pad, 16B aligned
#define ESTR 452         // per-elem stride: 16*28 + 4 → e-stride ≡ 4 banks mod 32
#define T    256

typedef float v2f __attribute__((ext_vector_type(2)));

// ws layout (floats): [0..575] A(24x24) | [576..2111] Wc(768x2) | [2112..2113] bc(2)

__global__ void prep_kernel(const int* __restrict__ ei, int ec,
                            const float* __restrict__ fcw1, const float* __restrict__ fcb1,
                            const float* __restrict__ fcw2, const float* __restrict__ fcb2,
                            float* __restrict__ ws) {
  int t = threadIdx.x;
  if (blockIdx.x == 0) {
    __shared__ float deg[NN];
    __shared__ float dinv[NN];
    __shared__ float As[NN*NN];
    __shared__ int s_is64;
    if (t == 0) s_is64 = 1;
    if (t < NN) deg[t] = 1.0f;            // self-loop contribution
    for (int k = t; k < NN*NN; k += T) As[k] = 0.0f;
    __syncthreads();
    // dtype sniff: int64 edge_index viewed as int32 has all odd (high) words == 0
    for (int k = t; k < 2*ec; k += T) {
      if (ei[2*k + 1] != 0) atomicExch(&s_is64, 0);
    }
    __syncthreads();
    int is64 = s_is64;
    for (int k = t; k < ec; k += T) {
      int d = is64 ? ei[2*(ec + k)] : ei[ec + k];
      atomicAdd(&deg[d], 1.0f);
    }
    __syncthreads();
    if (t < NN) dinv[t] = 1.0f / sqrtf(deg[t]);
    __syncthreads();
    for (int k = t; k < ec; k += T) {
      int s = is64 ? ei[2*k]        : ei[k];
      int d = is64 ? ei[2*(ec + k)] : ei[ec + k];
      atomicAdd(&As[d*NN + s], dinv[s]*dinv[d]);
    }
    if (t < NN) atomicAdd(&As[t*NN + t], dinv[t]*dinv[t]);  // self loop
    __syncthreads();
    for (int k = t; k < NN*NN; k += T) ws[k] = As[k];
    if (t < 2) {
      float acc = fcb2[t];
      for (int k = 0; k < 128; ++k) acc += fcb1[k]*fcw2[k*2 + t];
      ws[2112 + t] = acc;
    }
  } else {
    // Wc = fcw1 @ fcw2 : blocks 1..8 compute 96 rows each
    int r0 = (blockIdx.x - 1) * 96;
    for (int idx = t; idx < 96*2; idx += T) {
      int r = r0 + (idx >> 1), c = idx & 1;
      float acc = 0.f;
      for (int k = 0; k < 128; ++k) acc += fcw1[r*128 + k]*fcw2[k*2 + c];
      ws[576 + r*2 + c] = acc;
    }
  }
}

// Merged step: gbuf holds g_l = A @ h_{l-1} (FIN cols per elem).
// Thread (e, f, chunk): h_l col f = relu(g_l @ W + b) held as 12 float2 pairs
// (v_pk_fma_f32: 2 FMA/inst), BARRIER, then per row-pair A-mix (packed dot,
// horizontal add) → immediate float2 write in place.
// NOTE (R2-R14 post-mortems): per-thread state live ACROSS the barrier must
// stay <= ~24 VGPRs (hh[12] v2f) — larger variants (hh[24] v2f, h[6][8],
// TM=128, EPB=32) all made the allocator spill to scratch, up to 2.9 GB/
// dispatch (R14). This shape is the empirically spill-free optimum.
template<int FIN, int FOUT, int SPLIT>
__device__ __forceinline__ void merged_layer(const float* __restrict__ Ag, float* gbuf,
                                             const float* Ws, const float* bs, int t) {
  constexpr int NCOLS = EPB*FOUT;       // 64/64/128/128/256/256
  constexpr int CL    = NN/SPLIT;       // 6/6/12/12/24/24
  int col = t & (NCOLS - 1);
  int i0  = __builtin_amdgcn_readfirstlane((t / NCOLS) * CL);  // wave-uniform
  int e = col / FOUT;
  int f = col & (FOUT - 1);
  const float* ib = gbuf + e*ESTR;
  // W-mix (packed): full column of h_l as 12 float2, seeded with bias
  float bf = bs[f];
  v2f hh[12];
  #pragma unroll
  for (int k = 0; k < 12; ++k) hh[k] = (v2f){bf, bf};
  #pragma unroll
  for (int fi = 0; fi < FIN; ++fi) {
    float w = Ws[fi*FOUT + f];
    v2f w2 = (v2f){w, w};
    const float4* c4 = (const float4*)(ib + fi*CSTR);
    #pragma unroll
    for (int k = 0; k < 6; ++k) {
      float4 v = c4[k];
      v2f lo = (v2f){v.x, v.y};
      v2f hi = (v2f){v.z, v.w};
      hh[2*k]   = lo*w2 + hh[2*k];     // -ffp-contract=fast → v_pk_fma_f32
      hh[2*k+1] = hi*w2 + hh[2*k+1];
    }
  }
  {
    v2f z2 = (v2f){0.f, 0.f};
    #pragma unroll
    for (int k = 0; k < 12; ++k) hh[k] = __builtin_elementwise_max(hh[k], z2);  // v_pk_max_f32
  }
  __syncthreads();           // all gbuf reads complete before in-place overwrite
  // A-mix row-pair (packed dot) → write immediately; A rows 8B-aligned (96 B)
  float* ob = gbuf + e*ESTR + f*CSTR + i0;
  #pragma unroll
  for (int ii = 0; ii < CL; ii += 2) {
    const v2f* ArA = (const v2f*)(Ag + (i0 + ii)*NN);
    const v2f* ArB = (const v2f*)(Ag + (i0 + ii + 1)*NN);
    v2f a0 = (v2f){0.f, 0.f}, a1 = (v2f){0.f, 0.f};
    #pragma unroll
    for (int j = 0; j < 12; ++j) {
      a0 = ArA[j]*hh[j] + a0;
      a1 = ArB[j]*hh[j] + a1;
    }
    *(float2*)(ob + ii) = make_float2(a0.x + a0.y, a1.x + a1.y);
  }
}

__global__ __launch_bounds__(256, 4) void gcn_main(
    const float* __restrict__ x, const float* __restrict__ ws,
    const float* __restrict__ W1, const float* __restrict__ b1,
    const float* __restrict__ W2, const float* __restrict__ b2,
    const float* __restrict__ W3, const float* __restrict__ b3,
    const float* __restrict__ W4, const float* __restrict__ b4,
    const float* __restrict__ W5, const float* __restrict__ b5,
    const float* __restrict__ W6, const float* __restrict__ b6,
    const float* __restrict__ W7, const float* __restrict__ b7,
    float* __restrict__ out) {
  __shared__ __align__(16) float gbuf[EPB*ESTR];  // 28928 B, single in-place buffer
  __shared__ float Wsh[500];                      // W1..W6; W7 read from global/L1
  __shared__ __align__(16) float bsh[88];
  int t = threadIdx.x;

  // stage layer weights/biases into LDS
  {
    const float* Wp[6] = {W1,W2,W3,W4,W5,W6};
    const float* bp[7] = {b1,b2,b3,b4,b5,b6,b7};
    const int wsz[6] = {4,16,32,64,128,256};
    const int wof[6] = {0,4,20,52,116,244};
    const int bsz[7] = {4,4,8,8,16,16,32};
    const int bof[7] = {0,4,8,16,24,40,56};
    #pragma unroll
    for (int l = 0; l < 6; ++l) {
      for (int k = t; k < wsz[l]; k += T) Wsh[wof[l] + k] = Wp[l][k];
    }
    #pragma unroll
    for (int l = 0; l < 7; ++l) {
      if (t < bsz[l]) bsh[bof[l] + t] = bp[l][t];
    }
  }
  // stage x tile into column slot 1 of each elem (col 0 gets g1 = A@x)
  {
    const float* xg = x + (size_t)blockIdx.x * (EPB*NN);
    if (t < EPB*NN/4) {
      float4 v = ((const float4*)xg)[t];
      int e = t/6, k = t - e*6;
      ((float4*)(gbuf + e*ESTR + CSTR))[k] = v;
    }
  }
  __syncthreads();

  // g1 = A @ x : 384 tasks (e, i); A rows per-lane from global (2.3 KB, L1-hot)
  {
    int e = t & 15, i = t >> 4;          // i in 0..15
    const float4* xv = (const float4*)(gbuf + e*ESTR + CSTR);
    const float4* Ar = (const float4*)(ws + i*NN);
    float acc = 0.f;
    #pragma unroll
    for (int k = 0; k < 6; ++k) {
      float4 a = Ar[k]; float4 v = xv[k];
      acc += a.x*v.x + a.y*v.y + a.z*v.z + a.w*v.w;
    }
    gbuf[e*ESTR + i] = acc;
    if (t < 128) {
      int i2 = 16 + (t >> 4);            // i in 16..23
      const float4* Ar2 = (const float4*)(ws + i2*NN);
      float acc2 = 0.f;
      #pragma unroll
      for (int k = 0; k < 6; ++k) {
        float4 a = Ar2[k]; float4 v = xv[k];
        acc2 += a.x*v.x + a.y*v.y + a.z*v.z + a.w*v.w;
      }
      gbuf[e*ESTR + i2] = acc2;
    }
  }
  __syncthreads();

  merged_layer<1, 4, 4>(ws, gbuf, Wsh+0,   bsh+0,  t); __syncthreads();
  merged_layer<4, 4, 4>(ws, gbuf, Wsh+4,   bsh+4,  t); __syncthreads();
  merged_layer<4, 8, 2>(ws, gbuf, Wsh+20,  bsh+8,  t); __syncthreads();
  merged_layer<8, 8, 2>(ws, gbuf, Wsh+52,  bsh+16, t); __syncthreads();
  merged_layer<8,16, 1>(ws, gbuf, Wsh+116, bsh+24, t); __syncthreads();
  merged_layer<16,16,1>(ws, gbuf, Wsh+244, bsh+40, t); __syncthreads();

  // L7 + composed FC + log_softmax (column form, packed math):
  // hh as 12 float2 pairs; P-mix packs (p0,p1) into one float2 accumulator so
  // each h element costs one pk-fma.
  {
    const float* Wc = ws + 576;
    float bc0 = ws[2112], bc1 = ws[2113];
    #pragma unroll
    for (int r = 0; r < 2; ++r) {
      int col = t + r*T;               // 512 columns = 16 elems x 32 feats
      int e = col >> 5, f = col & 31;
      const float* ib = gbuf + e*ESTR;
      float bf = bsh[56 + f];
      v2f hh[12];
      #pragma unroll
      for (int k = 0; k < 12; ++k) hh[k] = (v2f){bf, bf};
      #pragma unroll
      for (int fi = 0; fi < 16; ++fi) {
        float w = W7[fi*32 + f];       // global, L1-cached, coalesced
        v2f w2 = (v2f){w, w};
        const float4* c4 = (const float4*)(ib + fi*CSTR);
        #pragma unroll
        for (int k = 0; k < 6; ++k) {
          float4 v = c4[k];
          v2f lo = (v2f){v.x, v.y};
          v2f hi = (v2f){v.z, v.w};
          hh[2*k]   = lo*w2 + hh[2*k];
          hh[2*k+1] = hi*w2 + hh[2*k+1];
        }
      }
      v2f p = (v2f){0.f, 0.f};         // (p0, p1)
      #pragma unroll
      for (int k = 0; k < 12; ++k) {
        float h0 = fmaxf(hh[k].x, 0.f);
        float h1 = fmaxf(hh[k].y, 0.f);
        v2f wcA = *(const v2f*)(Wc + ((2*k)*32 + f)*2);
        v2f wcB = *(const v2f*)(Wc + ((2*k + 1)*32 + f)*2);
        p = (v2f){h0, h0}*wcA + p;
        p = (v2f){h1, h1}*wcB + p;
      }
      float p0 = p.x, p1 = p.y;
      #pragma unroll
      for (int m = 1; m < 32; m <<= 1) {
        p0 += __shfl_xor(p0, m, 32);
        p1 += __shfl_xor(p1, m, 32);
      }
      if (f < 2) {
        float z0 = p0 + bc0, z1 = p1 + bc1;
        float mx = fmaxf(z0, z1);
        float lse = mx + logf(expf(z0 - mx) + expf(z1 - mx));
        int eg = blockIdx.x*EPB + e;
        out[eg*2 + f] = (f == 0 ? z0 : z1) - lse;
      }
    }
  }
}

extern "C" void kernel_launch(void* const* d_in, const int* in_sizes, int n_in,
                              void* d_out, int out_size, void* d_ws, size_t ws_size,
                              hipStream_t stream) {
  const float* x    = (const float*)d_in[0];
  const int*   ei   = (const int*)  d_in[1];
  const float* W1   = (const float*)d_in[2];  const float* b1 = (const float*)d_in[3];
  const float* W2   = (const float*)d_in[4];  const float* b2 = (const float*)d_in[5];
  const float* W3   = (const float*)d_in[6];  const float* b3 = (const float*)d_in[7];
  const float* W4   = (const float*)d_in[8];  const float* b4 = (const float*)d_in[9];
  const float* W5   = (const float*)d_in[10]; const float* b5 = (const float*)d_in[11];
  const float* W6   = (const float*)d_in[12]; const float* b6 = (const float*)d_in[13];
  const float* W7   = (const float*)d_in[14]; const float* b7 = (const float*)d_in[15];
  const float* fcw1 = (const float*)d_in[16]; const float* fcb1 = (const float*)d_in[17];
  const float* fcw2 = (const float*)d_in[18]; const float* fcb2 = (const float*)d_in[19];
  float* out = (float*)d_out;
  float* ws  = (float*)d_ws;
  int ec = in_sizes[1] / 2;        // 96 edges
  int B  = in_sizes[0] / NN;       // 32768

  hipLaunchKernelGGL(prep_kernel, dim3(9), dim3(T), 0, stream,
                     ei, ec, fcw1, fcb1, fcw2, fcb2, ws);
  hipLaunchKernelGGL(gcn_main, dim3(B/EPB), dim3(T), 0, stream,
                     x, ws, W1,b1, W2,b2, W3,b3, W4,b4, W5,b5, W6,b6, W7,b7, out);
}